// Round 7
// baseline (190.437 us; speedup 1.0000x reference)
//
#include <hip/hip_runtime.h>
#include <hip/hip_bf16.h>
#include <cstdint>
#include <cstddef>

#define BS 8
#define SEQ 1024
#define DMODEL 512
#define NHEADS 8
#define DHEAD 64
#define QBLK 16
#define PPAD 1032   // P bf16 row stride (elems): 16B-aligned, non-pathological banks

typedef float f32x4 __attribute__((ext_vector_type(4)));
typedef short bf16x8 __attribute__((ext_vector_type(8)));

static __device__ __forceinline__ unsigned short f2bf(float v) {
    __hip_bfloat16 hb = __float2bfloat16(v);
    return *reinterpret_cast<unsigned short*>(&hb);
}

// ---------------------------------------------------------------------------
// f32 -> bf16 conversion pre-pass (7 independent jobs, blockIdx.y selects)
// ---------------------------------------------------------------------------
struct CvtJob { const float* s; unsigned short* d; int n4; };

__global__ __launch_bounds__(256) void cvt_many(
    CvtJob j0, CvtJob j1, CvtJob j2, CvtJob j3, CvtJob j4, CvtJob j5, CvtJob j6)
{
    CvtJob j;
    switch (blockIdx.y) {
        case 0: j = j0; break; case 1: j = j1; break; case 2: j = j2; break;
        case 3: j = j3; break; case 4: j = j4; break; case 5: j = j5; break;
        default: j = j6; break;
    }
    for (int i = blockIdx.x * 256 + threadIdx.x; i < j.n4; i += gridDim.x * 256) {
        const float4 f = ((const float4*)j.s)[i];
        uint2 u;
        u.x = (unsigned)f2bf(f.x) | ((unsigned)f2bf(f.y) << 16);
        u.y = (unsigned)f2bf(f.z) | ((unsigned)f2bf(f.w) << 16);
        ((uint2*)j.d)[i] = u;
    }
}

// ---------------------------------------------------------------------------
// bf16 MFMA GEMM, tile 64M x 128N, BK=64, global_load_lds staging with
// XOR source-swizzle (chunk c8 ^= r&7) so frag ds_read_b128 is conflict-free.
// C[r][c] = sum_k A[r][k]*W[c][k]; epilogue modes (r5/r6-validated):
//  0: f32 row-major [M][512] + bias
//  1: bf16 head layout [b][h][l][dd], *scale (+bias)
//  2: bf16 transposed head layout [b][h][dd][l] (+bias)  [uint2 stores]
// ---------------------------------------------------------------------------
struct GArgs { const unsigned short* A; const unsigned short* W;
               const float* bias; void* C; float scale; int mode; };

__global__ __launch_bounds__(256) void gemm_mfma(GArgs g0, GArgs g1, GArgs g2) {
    __shared__ __align__(16) unsigned short As[64 * 64];
    __shared__ __align__(16) unsigned short Bs[128 * 64];

    const GArgs g = (blockIdx.z == 0) ? g0 : ((blockIdx.z == 1) ? g1 : g2);
    const int tid = threadIdx.x;
    const int w = tid >> 6, l = tid & 63, lr = l & 15, lg = l >> 4;
    const int bm = blockIdx.y * 64, bn = blockIdx.x * 128;
    const int mrow = (w & 1) * 32, ncol = (w >> 1) * 64;

    f32x4 acc[2][4];
#pragma unroll
    for (int mt = 0; mt < 2; ++mt)
#pragma unroll
        for (int nt = 0; nt < 4; ++nt) acc[mt][nt] = (f32x4)0.f;

    for (int k0 = 0; k0 < DMODEL; k0 += 64) {
#pragma unroll
        for (int i = 0; i < 2; ++i) {
            const int rbase = i * 32 + w * 8;
            const int r = rbase + (l >> 3);
            const unsigned short* src = g.A + (size_t)(bm + r) * DMODEL + k0
                                        + 8 * ((l & 7) ^ (r & 7));
            __builtin_amdgcn_global_load_lds((const unsigned int*)src,
                                             (unsigned int*)&As[rbase * 64], 16, 0, 0);
        }
#pragma unroll
        for (int i = 0; i < 4; ++i) {
            const int rbase = i * 32 + w * 8;
            const int r = rbase + (l >> 3);
            const unsigned short* src = g.W + (size_t)(bn + r) * DMODEL + k0
                                        + 8 * ((l & 7) ^ (r & 7));
            __builtin_amdgcn_global_load_lds((const unsigned int*)src,
                                             (unsigned int*)&Bs[rbase * 64], 16, 0, 0);
        }
        __syncthreads();
#pragma unroll
        for (int kk = 0; kk < 2; ++kk) {
            bf16x8 av[2], bv[4];
#pragma unroll
            for (int mt = 0; mt < 2; ++mt) {
                const int ra = mrow + mt * 16 + lr;
                av[mt] = *(const bf16x8*)&As[ra * 64 + 8 * ((kk * 4 + lg) ^ (ra & 7))];
            }
#pragma unroll
            for (int nt = 0; nt < 4; ++nt) {
                const int rb = ncol + nt * 16 + lr;
                bv[nt] = *(const bf16x8*)&Bs[rb * 64 + 8 * ((kk * 4 + lg) ^ (rb & 7))];
            }
#pragma unroll
            for (int mt = 0; mt < 2; ++mt)
#pragma unroll
                for (int nt = 0; nt < 4; ++nt)
                    acc[mt][nt] = __builtin_amdgcn_mfma_f32_16x16x32_bf16(
                        av[mt], bv[nt], acc[mt][nt], 0, 0, 0);
        }
        __syncthreads();
    }

    if (g.mode == 0) {
        float* C = (float*)g.C;
#pragma unroll
        for (int mt = 0; mt < 2; ++mt)
#pragma unroll
        for (int nt = 0; nt < 4; ++nt)
#pragma unroll
        for (int j = 0; j < 4; ++j) {
            const int r = bm + mrow + mt * 16 + lg * 4 + j;
            const int c = bn + ncol + nt * 16 + lr;
            C[(size_t)r * DMODEL + c] = acc[mt][nt][j] * g.scale
                                        + (g.bias ? g.bias[c] : 0.f);
        }
    } else if (g.mode == 1) {
        unsigned short* C = (unsigned short*)g.C;
#pragma unroll
        for (int mt = 0; mt < 2; ++mt)
#pragma unroll
        for (int nt = 0; nt < 4; ++nt)
#pragma unroll
        for (int j = 0; j < 4; ++j) {
            const int r = bm + mrow + mt * 16 + lg * 4 + j;
            const int c = bn + ncol + nt * 16 + lr;
            const float v = acc[mt][nt][j] * g.scale + (g.bias ? g.bias[c] : 0.f);
            const int b = r >> 10, ll = r & (SEQ - 1);
            const int h = c >> 6, dd = c & 63;
            C[((size_t)(b * NHEADS + h) * SEQ + ll) * DHEAD + dd] = f2bf(v);
        }
    } else {
        unsigned short* C = (unsigned short*)g.C;
#pragma unroll
        for (int mt = 0; mt < 2; ++mt)
#pragma unroll
        for (int nt = 0; nt < 4; ++nt) {
            const int c = bn + ncol + nt * 16 + lr;
            const int h = c >> 6, dd = c & 63;
            const int r0 = bm + mrow + mt * 16 + lg * 4;
            const int b = r0 >> 10, l0 = r0 & (SEQ - 1);
            unsigned short tmp[4];
#pragma unroll
            for (int j = 0; j < 4; ++j)
                tmp[j] = f2bf(acc[mt][nt][j] * g.scale + (g.bias ? g.bias[c] : 0.f));
            uint2 u;
            u.x = (unsigned)tmp[0] | ((unsigned)tmp[1] << 16);
            u.y = (unsigned)tmp[2] | ((unsigned)tmp[3] << 16);
            *(uint2*)&C[((size_t)(b * NHEADS + h) * DHEAD + dd) * SEQ + l0] = u;
        }
    }
}

// ---------------------------------------------------------------------------
// MFMA sparsemax attention, register-resident scores.
// Block = 16 q-rows of one (b,h); 4 waves. Wave w: QK^T key slice w*256 kept
// in acc regs. Newton tau: in-reg partials, shfl over lr, double-buffered LDS
// cross-wave combine (1 barrier/iter), tolerance break (tn - tau < 1e-5,
// block-uniform via 2 extra shfl stages).
// P = relu(acc - tau) written ONCE as bf16 to LDS (33 KB -> 4 blocks/CU);
// PV reads A-frags as ds_read_b128, V as B-frags from global Vt[b][h][d][l].
// ---------------------------------------------------------------------------
__global__ __launch_bounds__(256, 4) void attn_mfma(
    const unsigned short* __restrict__ Q, const unsigned short* __restrict__ K,
    const unsigned short* __restrict__ Vt, unsigned short* __restrict__ R)
{
    __shared__ __align__(16) unsigned short P[QBLK][PPAD];
    __shared__ float red_s[2][4][QBLK];
    __shared__ float red_c[2][4][QBLK];

    const int tid = threadIdx.x;
    const int w = tid >> 6, l = tid & 63, lr = l & 15, lg = l >> 4;

    // XCD-aware decode: xcd = flat&7 owns 512 consecutive nids (8 (b,h) pairs)
    const int flat = blockIdx.x;
    const int nid = (flat & 7) * 512 + (flat >> 3);
    const int q0 = (nid & 63) * QBLK;
    const int h = (nid >> 6) & (NHEADS - 1);
    const int b = nid >> 9;

    const size_t base = (size_t)(b * NHEADS + h) * SEQ * DHEAD;
    const unsigned short* Qp = Q + base;
    const unsigned short* Kp = K + base;

    const int ks = w * 256;   // wave's key slice

    // ---- QK^T into registers (validated contract); Q pre-scaled 1/8 ----
    const bf16x8 aq0 = *(const bf16x8*)(Qp + (size_t)(q0 + lr) * DHEAD + lg * 8);
    const bf16x8 aq1 = *(const bf16x8*)(Qp + (size_t)(q0 + lr) * DHEAD + 32 + lg * 8);
    f32x4 acc[16];
#pragma unroll
    for (int t = 0; t < 16; ++t) acc[t] = (f32x4)0.f;
#pragma unroll
    for (int t = 0; t < 16; ++t) {
        const unsigned short* kp = Kp + (size_t)(ks + t * 16 + lr) * DHEAD + lg * 8;
        const bf16x8 bk0 = *(const bf16x8*)(kp);
        const bf16x8 bk1 = *(const bf16x8*)(kp + 32);
        acc[t] = __builtin_amdgcn_mfma_f32_16x16x32_bf16(aq0, bk0, acc[t], 0, 0, 0);
        acc[t] = __builtin_amdgcn_mfma_f32_16x16x32_bf16(aq1, bk1, acc[t], 0, 0, 0);
    }
    // lane holds S[rows lg*4+j][cols ks + t*16 + lr], j=0..3

    // ---- hierarchical row max -> red buf 0 ----
    float mx[4];
#pragma unroll
    for (int j = 0; j < 4; ++j) mx[j] = acc[0][j];
#pragma unroll
    for (int t = 1; t < 16; ++t)
#pragma unroll
        for (int j = 0; j < 4; ++j) mx[j] = fmaxf(mx[j], acc[t][j]);
#pragma unroll
    for (int o = 1; o < 16; o <<= 1)
#pragma unroll
        for (int j = 0; j < 4; ++j) mx[j] = fmaxf(mx[j], __shfl_xor(mx[j], o));
    if (lr == 0) {
#pragma unroll
        for (int j = 0; j < 4; ++j) red_s[0][w][lg * 4 + j] = mx[j];
    }
    __syncthreads();
    float tau[4];
#pragma unroll
    for (int j = 0; j < 4; ++j) {
        const int r = lg * 4 + j;
        tau[j] = fmaxf(fmaxf(red_s[0][0][r], red_s[0][1][r]),
                       fmaxf(red_s[0][2][r], red_s[0][3][r])) - 1.0f;
    }
    // no barrier: iter 0 writes buf 1

    // ---- Newton on tau: monotone from max-1, 1 barrier/iter, tol break ----
    for (int it = 0; it < 16; ++it) {
        const int bb = (it + 1) & 1;
        float s[4] = {0.f, 0.f, 0.f, 0.f};
        float c[4] = {0.f, 0.f, 0.f, 0.f};
#pragma unroll
        for (int t = 0; t < 16; ++t)
#pragma unroll
            for (int j = 0; j < 4; ++j) {
                const bool ggt = acc[t][j] > tau[j];
                s[j] += ggt ? acc[t][j] : 0.f;
                c[j] += ggt ? 1.f : 0.f;
            }
#pragma unroll
        for (int o = 1; o < 16; o <<= 1)
#pragma unroll
            for (int j = 0; j < 4; ++j) {
                s[j] += __shfl_xor(s[j], o);
                c[j] += __shfl_xor(c[j], o);
            }
        if (lr == 0) {
#pragma unroll
            for (int j = 0; j < 4; ++j) {
                red_s[bb][w][lg * 4 + j] = s[j];
                red_c[bb][w][lg * 4 + j] = c[j];
            }
        }
        __syncthreads();
        float delta = -1.f;
#pragma unroll
        for (int j = 0; j < 4; ++j) {
            const int r = lg * 4 + j;
            const float st = red_s[bb][0][r] + red_s[bb][1][r]
                           + red_s[bb][2][r] + red_s[bb][3][r];
            const float ct = red_c[bb][0][r] + red_c[bb][1][r]
                           + red_c[bb][2][r] + red_c[bb][3][r];
            const float tn = (st - 1.f) / ct;   // ct >= 1 always (tau < row max)
            delta = fmaxf(delta, tn - tau[j]);
            tau[j] = tn;
        }
        // block-uniform convergence: max delta over all 16 rows (lg groups)
        delta = fmaxf(delta, __shfl_xor(delta, 16));
        delta = fmaxf(delta, __shfl_xor(delta, 32));
        if (delta < 1e-5f) break;   // uniform across block (same red sums)
    }

    // ---- write P = relu(acc - tau) as bf16 (the PV A operand) ----
#pragma unroll
    for (int t = 0; t < 16; ++t)
#pragma unroll
        for (int j = 0; j < 4; ++j)
            P[lg * 4 + j][ks + t * 16 + lr] = f2bf(fmaxf(acc[t][j] - tau[j], 0.f));
    __syncthreads();   // P complete — last barrier

    // ---- PV: wave w owns d-cols w*16..+15; V B-frags from global Vt ----
    const int dcol = w * 16;
    const unsigned short* VtP = Vt + ((size_t)(b * NHEADS + h) * DHEAD + dcol + lr) * SEQ
                                + lg * 8;
    f32x4 o = (f32x4)0.f;
    bf16x8 vb = *(const bf16x8*)(VtP);
#pragma unroll 4
    for (int kt = 0; kt < 32; ++kt) {
        const bf16x8 vcur = vb;
        if (kt + 1 < 32) vb = *(const bf16x8*)(VtP + (kt + 1) * 32);
        const bf16x8 pa = *(const bf16x8*)&P[lr][kt * 32 + lg * 8];
        __builtin_amdgcn_s_setprio(1);
        o = __builtin_amdgcn_mfma_f32_16x16x32_bf16(pa, vcur, o, 0, 0, 0);
        __builtin_amdgcn_s_setprio(0);
    }

    // ---- write O tile rows q0+lg*4+j, cols h*64+dcol+lr (bf16 for final GEMM)
#pragma unroll
    for (int j = 0; j < 4; ++j)
        R[((size_t)b * SEQ + q0 + lg * 4 + j) * DMODEL + h * DHEAD + dcol + lr] =
            f2bf(o[j]);
}

extern "C" void kernel_launch(void* const* d_in, const int* in_sizes, int n_in,
                              void* d_out, int out_size, void* d_ws, size_t ws_size,
                              hipStream_t stream) {
    const float* h_q = (const float*)d_in[0];
    const float* h_k = (const float*)d_in[1];
    const float* h_v = (const float*)d_in[2];
    const float* Wq  = (const float*)d_in[3];
    const float* Wk  = (const float*)d_in[4];
    const float* Wv  = (const float*)d_in[5];
    const float* bv  = (const float*)d_in[6];
    const float* Wf  = (const float*)d_in[7];
    const float* bf  = (const float*)d_in[8];
    float* out = (float*)d_out;

    const size_t perT = (size_t)BS * SEQ * DMODEL;   // 4,194,304 elements
    const size_t wN = (size_t)DMODEL * DMODEL;       // 262,144 elements
    unsigned short* hq_b = (unsigned short*)d_ws;    // bf16 inputs
    unsigned short* hk_b = hq_b + perT;
    unsigned short* hv_b = hk_b + perT;
    unsigned short* Qws  = hv_b + perT;              // projections (head layout)
    unsigned short* Kws  = Qws + perT;
    unsigned short* Vtw  = Kws + perT;               // transposed [b][h][d][l]
    unsigned short* Rws  = Vtw + perT;               // attn output (bf16)
    unsigned short* Wqb  = Rws + perT;               // bf16 weights
    unsigned short* Wkb  = Wqb + wN;
    unsigned short* Wvb  = Wkb + wN;
    unsigned short* Wfb  = Wvb + wN;

    // 1) convert inputs + weights to bf16
    {
        CvtJob j0{h_q, hq_b, (int)(perT / 4)};
        CvtJob j1{h_k, hk_b, (int)(perT / 4)};
        CvtJob j2{h_v, hv_b, (int)(perT / 4)};
        CvtJob j3{Wq, Wqb, (int)(wN / 4)};
        CvtJob j4{Wk, Wkb, (int)(wN / 4)};
        CvtJob j5{Wv, Wvb, (int)(wN / 4)};
        CvtJob j6{Wf, Wfb, (int)(wN / 4)};
        cvt_many<<<dim3(512, 7), 256, 0, stream>>>(j0, j1, j2, j3, j4, j5, j6);
    }

    // 2) fused Q/K/V projections (bf16 MFMA, gload_lds staging)
    {
        GArgs gq{hq_b, Wqb, nullptr, Qws, 0.125f, 1};
        GArgs gk{hk_b, Wkb, nullptr, Kws, 1.0f, 1};
        GArgs gv{hv_b, Wvb, bv,      Vtw, 1.0f, 2};
        gemm_mfma<<<dim3(DMODEL / 128, BS * SEQ / 64, 3), 256, 0, stream>>>(gq, gk, gv);
    }

    // 3) attention
    attn_mfma<<<dim3(BS * NHEADS * (SEQ / QBLK)), 256, 0, stream>>>(Qws, Kws, Vtw, Rws);

    // 4) output projection
    {
        GArgs gf{Rws, Wfb, bf, out, 1.0f, 0};
        gemm_mfma<<<dim3(DMODEL / 128, BS * SEQ / 64, 1), 256, 0, stream>>>(gf, gf, gf);
    }
}